// Round 1
// baseline (4758.918 us; speedup 1.0000x reference)
//
#include <hip/hip_runtime.h>

// ---------------------------------------------------------------------------
// ReLU-RNN (B=256, T=512, I=64, H=512, O=24), fp32 in/out.
//
// Persistent-kernel design:
//   16 groups x 16 blocks (grid=256 blocks, 128 thr = 2 waves each).
//   Group g owns batch rows [16g, 16g+16); member m owns W rows [32m, 32m+32).
//   W_ext = [W_hh | W_ih] (K=576) held in VGPRs as bf16 hi/lo MFMA B-frags.
//   Per step: C[16b x 32i] = A[16b x 576k] * B via mfma_f32_16x16x32_bf16,
//   3-term bf16x3 emulation (hi*hi + lo*hi + hi*lo) for ~2^-17 per-step error.
//   h exchanged through a double-buffered global buffer (hi & lo bf16 planes,
//   row = [h(512) | x_t(64)]), group barrier via agent-scope atomic counter.
// ---------------------------------------------------------------------------

#define T_STEPS 512
#define BATCH   256
#define HID     512
#define INF     64
#define OUTF    24
#define KE      576                       // 512 h + 64 x columns
#define ROW_S   576                       // row length in shorts
#define PLANE_S (BATCH * ROW_S)           // 147456 shorts per plane
#define PAR_S   (2 * PLANE_S)             // hi+lo planes per parity
#define EX_BYTES (2 * PAR_S * 2)          // 1179648 bytes (2 parities)
#define MAGIC   0x13579BDFu

typedef short  short8  __attribute__((ext_vector_type(8)));
typedef float  floatx4 __attribute__((ext_vector_type(4)));

__device__ __forceinline__ unsigned short f2bf(float x) {
    unsigned u = __float_as_uint(x);
    u = (u + 0x7fffu + ((u >> 16) & 1u)) >> 16;   // RNE
    return (unsigned short)u;
}
__device__ __forceinline__ float bf2f(unsigned short h) {
    return __uint_as_float(((unsigned)h) << 16);
}

__global__ __launch_bounds__(128, 1) void rnn_persistent(
    const float* __restrict__ x,     const float* __restrict__ W_ih,
    const float* __restrict__ W_hh,  const float* __restrict__ b_ih,
    const float* __restrict__ b_hh,  const float* __restrict__ fc_w,
    const float* __restrict__ fc_b,  float* __restrict__ out,
    unsigned char* __restrict__ ws)
{
    const int tid  = threadIdx.x;
    const int lane = tid & 63;
    const int nt   = tid >> 6;        // wave id 0/1 -> N-tile
    const int n    = lane & 15;
    const int quad = lane >> 4;

    // XCD-local group swizzle (assumes bid%8 -> XCD; correctness-independent)
    const int bid = blockIdx.x;
    const int c = bid & 7, q = bid >> 3;
    const int mem = q & 15, u = q >> 4;
    const int g = c + 8 * u;          // group 0..15

    unsigned short* ex = (unsigned short*)ws;
    unsigned* cnt  = (unsigned*)(ws + EX_BYTES + g * 256);
    unsigned* flag = (unsigned*)(ws + EX_BYTES + g * 256 + 128);

    // ---- group init handshake (ws is poisoned 0xAA each launch) ----
    if (mem == 0 && tid == 0) {
        __hip_atomic_store(cnt, 0u, __ATOMIC_RELAXED, __HIP_MEMORY_SCOPE_AGENT);
        __hip_atomic_store(flag, MAGIC, __ATOMIC_RELEASE, __HIP_MEMORY_SCOPE_AGENT);
    }
    if (tid == 0) {
        while (__hip_atomic_load(flag, __ATOMIC_ACQUIRE, __HIP_MEMORY_SCOPE_AGENT) != MAGIC) {}
    }
    __syncthreads();

    // ---- W fragments: rows r0..r0+15 for this wave, bf16 hi/lo, in VGPRs ----
    const int r0   = mem * 32 + nt * 16;
    const int wrow = r0 + n;                   // B-operand: lane&15 = n = W row
    short8 Whi[18], Wlo[18];
    #pragma unroll
    for (int kt = 0; kt < 18; ++kt) {
        const float* p = (kt < 16) ? (W_hh + wrow * 512 + kt * 32 + quad * 8)
                                   : (W_ih + wrow * 64 + (kt - 16) * 32 + quad * 8);
        #pragma unroll
        for (int j = 0; j < 8; ++j) {
            float f = p[j];
            unsigned short h = f2bf(f);
            Whi[kt][j] = (short)h;
            Wlo[kt][j] = (short)f2bf(f - bf2f(h));
        }
    }
    const float bias_i = b_ih[wrow] + b_hh[wrow];   // epilogue col n -> row wrow

    // ---- prologue: parity-0 buffer = [h=0 | x_0] for this member's row ----
    const int b_row = g * 16 + mem;
    {
        unsigned* rowhi = (unsigned*)(ex + 0 * PLANE_S + b_row * ROW_S);
        unsigned* rowlo = (unsigned*)(ex + 1 * PLANE_S + b_row * ROW_S);
        for (int idx = tid; idx < 256; idx += 128) { rowhi[idx] = 0u; rowlo[idx] = 0u; }
        if (tid < 64) {
            float xv = x[(b_row * T_STEPS + 0) * INF + tid];
            unsigned short h = f2bf(xv);
            ex[0 * PLANE_S + b_row * ROW_S + 512 + tid] = h;
            ex[1 * PLANE_S + b_row * ROW_S + 512 + tid] = f2bf(xv - bf2f(h));
        }
    }

    auto barrier = [&](int bnum) {
        __syncthreads();                       // drains vmcnt -> stores in L2
        if (tid == 0) {
            __hip_atomic_fetch_add(cnt, 1u, __ATOMIC_RELEASE, __HIP_MEMORY_SCOPE_AGENT);
            const unsigned tgt = 16u * (unsigned)bnum;
            while (__hip_atomic_load(cnt, __ATOMIC_ACQUIRE, __HIP_MEMORY_SCOPE_AGENT) < tgt) {}
        }
        __syncthreads();
    };
    barrier(1);

    // ---- main recurrence ----
    for (int t = 0; t < T_STEPS; ++t) {
        const int par = t & 1, par1 = par ^ 1;
        const unsigned short* Ahi = ex + par * PAR_S + 0 * PLANE_S + (g * 16) * ROW_S;
        const unsigned short* Alo = ex + par * PAR_S + 1 * PLANE_S + (g * 16) * ROW_S;
        // A-operand: lane&15 = m = batch-local row, k = kt*32 + quad*8 + j
        const short8* ahp = (const short8*)(Ahi + n * ROW_S + quad * 8);
        const short8* alp = (const short8*)(Alo + n * ROW_S + quad * 8);

        floatx4 c0 = {0.f,0.f,0.f,0.f}, c1 = {0.f,0.f,0.f,0.f}, c2 = {0.f,0.f,0.f,0.f};
        #pragma unroll
        for (int kt = 0; kt < 18; ++kt) {
            short8 ah = ahp[kt * 4];           // kt*32 shorts = kt*4 short8
            short8 al = alp[kt * 4];
            c0 = __builtin_amdgcn_mfma_f32_16x16x32_bf16(ah, Whi[kt], c0, 0, 0, 0);
            c1 = __builtin_amdgcn_mfma_f32_16x16x32_bf16(al, Whi[kt], c1, 0, 0, 0);
            c2 = __builtin_amdgcn_mfma_f32_16x16x32_bf16(ah, Wlo[kt], c2, 0, 0, 0);
        }

        // epilogue: D col = lane&15 -> output i = wrow; row = quad*4+r = batch
        floatx4 cs = c0 + c1 + c2;
        unsigned short* Ohi = ex + par1 * PAR_S + 0 * PLANE_S;
        unsigned short* Olo = ex + par1 * PAR_S + 1 * PLANE_S;
        #pragma unroll
        for (int r = 0; r < 4; ++r) {
            float v = cs[r] + bias_i;
            v = v > 0.f ? v : 0.f;
            const int br = g * 16 + quad * 4 + r;
            unsigned short h = f2bf(v);
            Ohi[br * ROW_S + wrow] = h;
            Olo[br * ROW_S + wrow] = f2bf(v - bf2f(h));
        }
        // stage x_{t+1} into the buffer consumed next step
        if (t + 1 < T_STEPS && tid < 64) {
            float xv = x[(b_row * T_STEPS + (t + 1)) * INF + tid];
            unsigned short h = f2bf(xv);
            Ohi[b_row * ROW_S + 512 + tid] = h;
            Olo[b_row * ROW_S + 512 + tid] = f2bf(xv - bf2f(h));
        }
        barrier(t + 2);
    }

    // ---- fc on h_last (in parity 0): member m does its own batch row ----
    {
        const unsigned short* Hhi = ex + 0 * PLANE_S + b_row * ROW_S;
        const unsigned short* Hlo = ex + 1 * PLANE_S + b_row * ROW_S;
        float hv[8];
        const short8 h8 = *(const short8*)(Hhi + lane * 8);
        const short8 l8 = *(const short8*)(Hlo + lane * 8);
        #pragma unroll
        for (int j = 0; j < 8; ++j)
            hv[j] = bf2f((unsigned short)h8[j]) + bf2f((unsigned short)l8[j]);

        for (int oo = 0; oo < 12; ++oo) {
            const int o = nt * 12 + oo;
            const float* wp = fc_w + o * 512 + lane * 8;
            float s = 0.f;
            #pragma unroll
            for (int j = 0; j < 8; ++j) s += hv[j] * wp[j];
            #pragma unroll
            for (int d = 1; d < 64; d <<= 1) s += __shfl_xor(s, d, 64);
            if (lane == 0) out[b_row * OUTF + o] = s + fc_b[o];
        }
    }
}

extern "C" void kernel_launch(void* const* d_in, const int* in_sizes, int n_in,
                              void* d_out, int out_size, void* d_ws, size_t ws_size,
                              hipStream_t stream) {
    (void)in_sizes; (void)n_in; (void)out_size; (void)ws_size;
    const float* x    = (const float*)d_in[0];
    const float* W_ih = (const float*)d_in[1];
    const float* W_hh = (const float*)d_in[2];
    const float* b_ih = (const float*)d_in[3];
    const float* b_hh = (const float*)d_in[4];
    const float* fc_w = (const float*)d_in[5];
    const float* fc_b = (const float*)d_in[6];
    rnn_persistent<<<256, 128, 0, stream>>>(x, W_ih, W_hh, b_ih, b_hh,
                                            fc_w, fc_b, (float*)d_out,
                                            (unsigned char*)d_ws);
}

// Round 3
// 2912.274 us; speedup vs baseline: 1.6341x; 1.6341x over previous
//
#include <hip/hip_runtime.h>

// ---------------------------------------------------------------------------
// ReLU-RNN (B=256, T=512, I=64, H=512, O=24), fp32 in/out.  Round 3
// (= round-2 design; compile fix: ushort4 typedef renamed to bfx4).
//
// 16 groups (16 batch rows each) x 8 members (64 hid cols each) = 128 blocks
// of 256 threads (4 waves; wave w owns cols m*64+w*16..+16).
// W_ext=[W_hh|W_ih] (K=576) lives in VGPRs as bf16 hi/lo MFMA B-frags.
// Per step: stage A=[h|x_t] (bf16 hi/lo) into LDS once, 4 waves MFMA from it.
// Exchange protocol is FENCELESS: all h traffic uses relaxed agent-scope
// atomics (write-through / cache-bypass at the L3 coherence point); producer
// sets a per-member flag after __syncthreads (vmcnt drained => data at L3);
// consumers poll 8 flags with relaxed loads.  No RMW, no wbl2, no buffer_inv.
// ---------------------------------------------------------------------------

#define T_STEPS 512
#define NG      16               // groups (batch/16)
#define NM      8                // members per group (512 cols / 64)
#define SLAB    32768            // bytes per (parity, group): 2 planes x 16x512 bf16
#define FLAGS_OFF (2 * NG * SLAB)            // 1 MiB
// LDS layout (bytes): Ah rows 16 x stride 1040 (512 shorts + 8 pad), Al next;
// Xh rows 16 x stride 144 (64 shorts + 8 pad), Xl next.
#define LA_STRIDE 1040
#define LA_PLANE  16640          // 16*1040
#define LX_OFF    33280          // 2*LA_PLANE
#define LX_STRIDE 144
#define LX_PLANE  2304           // 16*144

typedef short          short8  __attribute__((ext_vector_type(8)));
typedef unsigned short bfx4    __attribute__((ext_vector_type(4)));
typedef float          floatx4 __attribute__((ext_vector_type(4)));
typedef unsigned long long ull;

__device__ __forceinline__ unsigned short f2bf(float x) {
    unsigned u = __float_as_uint(x);
    u = (u + 0x7fffu + ((u >> 16) & 1u)) >> 16;   // RNE
    return (unsigned short)u;
}
__device__ __forceinline__ float bf2f(unsigned short h) {
    return __uint_as_float(((unsigned)h) << 16);
}
__device__ __forceinline__ void st_wt_u16(void* p, unsigned short v) {
    __hip_atomic_store((unsigned short*)p, v, __ATOMIC_RELAXED, __HIP_MEMORY_SCOPE_AGENT);
}
__device__ __forceinline__ void st_wt_u64(void* p, ull v) {
    __hip_atomic_store((ull*)p, v, __ATOMIC_RELAXED, __HIP_MEMORY_SCOPE_AGENT);
}
__device__ __forceinline__ ull ld_cp_u64(const void* p) {   // coherence-point load
    return __hip_atomic_load((const ull*)p, __ATOMIC_RELAXED, __HIP_MEMORY_SCOPE_AGENT);
}

__global__ __launch_bounds__(256, 1) void rnn_persistent(
    const float* __restrict__ x,     const float* __restrict__ W_ih,
    const float* __restrict__ W_hh,  const float* __restrict__ b_ih,
    const float* __restrict__ b_hh,  const float* __restrict__ fc_w,
    const float* __restrict__ fc_b,  float* __restrict__ out,
    unsigned char* __restrict__ ws)
{
    const int tid  = threadIdx.x;
    const int lane = tid & 63;
    const int w    = tid >> 6;        // wave 0..3
    const int n    = lane & 15;
    const int quad = lane >> 4;

    // XCD co-location: members of a group share bid%8 (likely same XCD -> L2
    // sharing of staged slabs). Correctness does not depend on this mapping.
    const int bid = blockIdx.x;
    const int c = bid & 7, j = bid >> 3;
    const int g = c * 2 + (j & 1);    // group 0..15
    const int m = j >> 1;             // member 0..7

    unsigned char* ex = (unsigned char*)ws;
    int* flags = (int*)(ex + FLAGS_OFF) + g * NM;

    __shared__ __align__(16) unsigned char smem[LX_OFF + 2 * LX_PLANE];

    // ---- W fragments: wave w holds cols (=W rows) m*64+w*16 .. +16 ----
    const int wrow = m * 64 + w * 16 + n;
    short8 Whi[18], Wlo[18];
    #pragma unroll
    for (int kt = 0; kt < 18; ++kt) {
        const float* p = (kt < 16) ? (W_hh + wrow * 512 + kt * 32 + quad * 8)
                                   : (W_ih + wrow * 64 + (kt - 16) * 32 + quad * 8);
        #pragma unroll
        for (int jj = 0; jj < 8; ++jj) {
            float f = p[jj];
            unsigned short h = f2bf(f);
            Whi[kt][jj] = (short)h;
            Wlo[kt][jj] = (short)f2bf(f - bf2f(h));
        }
    }
    const float bias_i = b_ih[wrow] + b_hh[wrow];

    // ---- init: member m zeros its 4 KB of slab(parity 0, g), write-through;
    //      then own flag = 0 (ws poison 0xAAAAAAAA is negative => "not ready")
    {
        unsigned char* z = ex + g * SLAB + m * 4096 + tid * 16;
        st_wt_u64(z, 0ull);
        st_wt_u64(z + 8, 0ull);
    }
    __syncthreads();                   // vmcnt(0): zeros are at coherence point
    if (tid == 0)
        __hip_atomic_store(&flags[m], 0, __ATOMIC_RELAXED, __HIP_MEMORY_SCOPE_AGENT);

    // ---- main recurrence: step t consumes h_t (parity t&1) + x_t,
    //      produces h_{t+1} (parity (t+1)&1) ----
    const int xrow = tid >> 4, xi4 = tid & 15;
    for (int t = 0; t < T_STEPS; ++t) {
        // x_t prefetch: independent of flags, issue before polling
        const float4 xv = ((const float4*)(x + ((size_t)(g * 16 + xrow) * T_STEPS + t) * 64))[xi4];

        // poll: thread p waits for member p to have completed step t
        if (tid < NM) {
            while (__hip_atomic_load(&flags[tid], __ATOMIC_RELAXED,
                                     __HIP_MEMORY_SCOPE_AGENT) < t) {}
        }
        __syncthreads();

        // stage A (h planes) global->LDS via coherence-point 8B loads
        const unsigned char* slab = ex + ((t & 1) * NG + g) * SLAB;
        #pragma unroll
        for (int rnd = 0; rnd < 16; ++rnd) {
            const int c8 = rnd * 256 + tid;              // 0..4095 8B-chunks
            ull v = ld_cp_u64(slab + c8 * 8);
            const int plane = c8 >> 11, rc = c8 & 2047;
            const int row = rc >> 7, col8 = rc & 127;
            *(ull*)(smem + plane * LA_PLANE + row * LA_STRIDE + col8 * 8) = v;
        }
        // stage x_t (convert fp32 -> bf16 hi/lo)
        {
            bfx4 hi4, lo4;
            #pragma unroll
            for (int k = 0; k < 4; ++k) {
                float f = (k == 0) ? xv.x : (k == 1) ? xv.y : (k == 2) ? xv.z : xv.w;
                unsigned short h = f2bf(f);
                hi4[k] = h;
                lo4[k] = f2bf(f - bf2f(h));
            }
            *(bfx4*)(smem + LX_OFF + xrow * LX_STRIDE + xi4 * 8) = hi4;
            *(bfx4*)(smem + LX_OFF + LX_PLANE + xrow * LX_STRIDE + xi4 * 8) = lo4;
        }
        __syncthreads();

        // compute: C[16 batch x 16 cols] over K=576, bf16x3
        floatx4 c0 = {0.f,0.f,0.f,0.f}, c1 = {0.f,0.f,0.f,0.f}, c2 = {0.f,0.f,0.f,0.f};
        #pragma unroll
        for (int kt = 0; kt < 16; ++kt) {
            const unsigned char* ba = smem + n * LA_STRIDE + kt * 64 + quad * 16;
            short8 ah = *(const short8*)(ba);
            short8 al = *(const short8*)(ba + LA_PLANE);
            c0 = __builtin_amdgcn_mfma_f32_16x16x32_bf16(ah, Whi[kt], c0, 0, 0, 0);
            c1 = __builtin_amdgcn_mfma_f32_16x16x32_bf16(al, Whi[kt], c1, 0, 0, 0);
            c2 = __builtin_amdgcn_mfma_f32_16x16x32_bf16(ah, Wlo[kt], c2, 0, 0, 0);
        }
        #pragma unroll
        for (int kt = 16; kt < 18; ++kt) {
            const unsigned char* ba = smem + LX_OFF + n * LX_STRIDE + (kt - 16) * 64 + quad * 16;
            short8 ah = *(const short8*)(ba);
            short8 al = *(const short8*)(ba + LX_PLANE);
            c0 = __builtin_amdgcn_mfma_f32_16x16x32_bf16(ah, Whi[kt], c0, 0, 0, 0);
            c1 = __builtin_amdgcn_mfma_f32_16x16x32_bf16(al, Whi[kt], c1, 0, 0, 0);
            c2 = __builtin_amdgcn_mfma_f32_16x16x32_bf16(ah, Wlo[kt], c2, 0, 0, 0);
        }

        // epilogue: D col=lane&15 -> hid col wrow; row=quad*4+r -> batch row.
        // Write-through stores (consecutive n lanes -> 32B runs).
        unsigned char* oslab = ex + ((~t & 1) * NG + g) * SLAB;
        const floatx4 cs = c0 + c1 + c2;
        #pragma unroll
        for (int r = 0; r < 4; ++r) {
            float v = cs[r] + bias_i;
            v = v > 0.f ? v : 0.f;
            const int row = quad * 4 + r;
            unsigned short h = f2bf(v);
            st_wt_u16(oslab + row * 1024 + wrow * 2, h);
            st_wt_u16(oslab + 16384 + row * 1024 + wrow * 2, f2bf(v - bf2f(h)));
        }
        __syncthreads();               // vmcnt(0): h_{t+1} is at coherence point
        if (tid == 0)
            __hip_atomic_store(&flags[m], t + 1, __ATOMIC_RELAXED,
                               __HIP_MEMORY_SCOPE_AGENT);
    }

    // ---- fc on h_T (parity 0): wait all members at 512, stage h, dot ----
    if (tid < NM) {
        while (__hip_atomic_load(&flags[tid], __ATOMIC_RELAXED,
                                 __HIP_MEMORY_SCOPE_AGENT) < T_STEPS) {}
    }
    __syncthreads();
    {
        const unsigned char* slab = ex + g * SLAB;     // parity 0
        #pragma unroll
        for (int rnd = 0; rnd < 16; ++rnd) {
            const int c8 = rnd * 256 + tid;
            ull v = ld_cp_u64(slab + c8 * 8);
            const int plane = c8 >> 11, rc = c8 & 2047;
            const int row = rc >> 7, col8 = rc & 127;
            *(ull*)(smem + plane * LA_PLANE + row * LA_STRIDE + col8 * 8) = v;
        }
    }
    __syncthreads();
    // member m: batch-local rows [2m, 2m+2), all 24 outs; threads 0..47
    if (tid < 48) {
        const int row = m * 2 + tid / 24;
        const int o   = tid % 24;
        const float* wp = fc_w + o * 512;
        float s = 0.f;
        for (int k = 0; k < 512; k += 4) {
            bfx4 hv = *(const bfx4*)(smem + row * LA_STRIDE + k * 2);
            bfx4 lv = *(const bfx4*)(smem + LA_PLANE + row * LA_STRIDE + k * 2);
            const float4 wv = *(const float4*)(wp + k);
            s += (bf2f(hv[0]) + bf2f(lv[0])) * wv.x;
            s += (bf2f(hv[1]) + bf2f(lv[1])) * wv.y;
            s += (bf2f(hv[2]) + bf2f(lv[2])) * wv.z;
            s += (bf2f(hv[3]) + bf2f(lv[3])) * wv.w;
        }
        out[(g * 16 + row) * 24 + o] = s + fc_b[o];
    }
}

extern "C" void kernel_launch(void* const* d_in, const int* in_sizes, int n_in,
                              void* d_out, int out_size, void* d_ws, size_t ws_size,
                              hipStream_t stream) {
    (void)in_sizes; (void)n_in; (void)out_size; (void)ws_size;
    const float* x    = (const float*)d_in[0];
    const float* W_ih = (const float*)d_in[1];
    const float* W_hh = (const float*)d_in[2];
    const float* b_ih = (const float*)d_in[3];
    const float* b_hh = (const float*)d_in[4];
    const float* fc_w = (const float*)d_in[5];
    const float* fc_b = (const float*)d_in[6];
    rnn_persistent<<<128, 256, 0, stream>>>(x, W_ih, W_hh, b_ih, b_hh,
                                            fc_w, fc_b, (float*)d_out,
                                            (unsigned char*)d_ws);
}

// Round 5
// 2657.560 us; speedup vs baseline: 1.7907x; 1.0958x over previous
//
#include <hip/hip_runtime.h>

// ---------------------------------------------------------------------------
// ReLU-RNN (B=256, T=512, I=64, H=512, O=24), fp32 in/out.  Round 5.
//
// 16 groups (16 batch rows) x 8 members (64 hid cols) = 128 blocks x 256 thr.
// vs round 4 (hang suspect):
//  * Flags ALWAYS agent-scope (L3) - signalling never depends on XCD verdict.
//  * All spin loops bounded (deadlock -> visible wrong result, never a hang).
//  * s_getreg XCC_ID via numeric builtin encoding (no symbolic hwreg asm).
//  * 3 syncs/step: MFMA -> global stores -> sync -> flag + own-LDS writes.
// Fast path (group's 8 members on one XCD): h data via plain write-through
// stores + sc0 loads (XCD L2).  Slow path: agent-scope L3 (round-3 protocol).
// Batched async staging: 14 loads in flight, one vmcnt(0), then LDS stores.
// ---------------------------------------------------------------------------

#define T_STEPS 512
#define NG      16
#define NM      8
#define SLAB    32768                    // 2 planes x 16 rows x 512 cols bf16
#define EX_BYTES (2 * NG * SLAB)         // 1 MiB (2 parities)
#define FLAGS_OFF EX_BYTES
#define NEG_OFF  (FLAGS_OFF + NG * 64)
#define MAGIC   0x13579BDFu
#define POLL_CAP 200000
#define NEG_CAP  20000000

#define LA_STRIDE 1040
#define LA_PLANE  16640                  // 16*1040
#define LX_OFF    33280                  // 2*LA_PLANE
#define LX_STRIDE 144
#define LX_PLANE  2304                   // 16*144

typedef short          short8  __attribute__((ext_vector_type(8)));
typedef unsigned short bfx4    __attribute__((ext_vector_type(4)));
typedef float          floatx4 __attribute__((ext_vector_type(4)));
typedef unsigned long long ull;

__device__ __forceinline__ unsigned short f2bf(float x) {
    unsigned u = __float_as_uint(x);
    u = (u + 0x7fffu + ((u >> 16) & 1u)) >> 16;   // RNE
    return (unsigned short)u;
}
__device__ __forceinline__ float bf2f(unsigned short h) {
    return __uint_as_float(((unsigned)h) << 16);
}
// ---- agent-scope (L3 coherence point) ops -------------------------------
__device__ __forceinline__ void st_ag_u16(void* p, unsigned short v) {
    __hip_atomic_store((unsigned short*)p, v, __ATOMIC_RELAXED, __HIP_MEMORY_SCOPE_AGENT);
}
__device__ __forceinline__ void st_ag_u32(void* p, unsigned v) {
    __hip_atomic_store((unsigned*)p, v, __ATOMIC_RELAXED, __HIP_MEMORY_SCOPE_AGENT);
}
__device__ __forceinline__ void st_ag_u64(void* p, ull v) {
    __hip_atomic_store((ull*)p, v, __ATOMIC_RELAXED, __HIP_MEMORY_SCOPE_AGENT);
}
__device__ __forceinline__ unsigned ld_ag_u32(const void* p) {
    return __hip_atomic_load((const unsigned*)p, __ATOMIC_RELAXED, __HIP_MEMORY_SCOPE_AGENT);
}
__device__ __forceinline__ int ld_ag_i32(const void* p) {
    return __hip_atomic_load((const int*)p, __ATOMIC_RELAXED, __HIP_MEMORY_SCOPE_AGENT);
}
// ---- L2-scope (intra-XCD) async load: bypass L1 only --------------------
__device__ __forceinline__ ull ld_l2_u64_async(const void* p) {
    ull v;
    asm volatile("global_load_dwordx2 %0, %1, off sc0" : "=v"(v) : "v"(p) : "memory");
    return v;
}
// ---- L3 async load (bypass L1+L2) ---------------------------------------
__device__ __forceinline__ ull ld_l3_u64_async(const void* p) {
    ull v;
    asm volatile("global_load_dwordx2 %0, %1, off sc0 sc1" : "=v"(v) : "v"(p) : "memory");
    return v;
}
__device__ __forceinline__ void wait_vm0() {
    asm volatile("s_waitcnt vmcnt(0)" ::: "memory");
}
// poll until flag in {want, want+1}; bounded (escape -> visible failure)
__device__ __forceinline__ void poll_flag(const unsigned* p, unsigned want) {
    int it = 0;
    for (;;) {
        unsigned f = ld_ag_u32(p);
        if (f == want || f == want + 1u) return;
        if (++it >= POLL_CAP) return;
    }
}

__global__ __launch_bounds__(256, 1) void rnn_persistent(
    const float* __restrict__ x,     const float* __restrict__ W_ih,
    const float* __restrict__ W_hh,  const float* __restrict__ b_ih,
    const float* __restrict__ b_hh,  const float* __restrict__ fc_w,
    const float* __restrict__ fc_b,  float* __restrict__ out,
    unsigned char* __restrict__ ws)
{
    const int tid  = threadIdx.x;
    const int lane = tid & 63;
    const int w    = tid >> 6;        // wave 0..3
    const int n    = lane & 15;
    const int quad = lane >> 4;

    unsigned char* ex = (unsigned char*)ws;
    __shared__ __align__(16) unsigned char smem[LX_OFF + 2 * LX_PLANE];
    __shared__ int sh_g, sh_m, sh_fast;
    __shared__ unsigned sh_nonce;

    // ================= negotiation (once per launch) ======================
    unsigned char* neg = ex + NEG_OFF;
    unsigned* magic   = (unsigned*)(neg + 0);
    unsigned* nonce_p = (unsigned*)(neg + 4);
    int*      ovf     = (int*)(neg + 8);
    int*      cnt     = (int*)(neg + 16);     // 8 ints
    int*      table   = (int*)(neg + 64);     // 128 ints

    if (tid == 0) {
        if (blockIdx.x == 0) {
            for (int i = 0; i < 128; ++i) st_ag_u32(&table[i], 0u);
            for (int i = 0; i < 8; ++i)  st_ag_u32(&cnt[i], 0u);
            st_ag_u32(ovf, 0u);
            unsigned nn = (unsigned)__builtin_amdgcn_s_memrealtime() | 1u;
            st_ag_u32(nonce_p, nn);
            __hip_atomic_store(magic, MAGIC, __ATOMIC_RELEASE, __HIP_MEMORY_SCOPE_AGENT);
        }
        { int it = 0; while (ld_ag_u32(magic) != MAGIC && ++it < NEG_CAP) {} }
        sh_nonce = ld_ag_u32(nonce_p);
        // HW_REG_XCC_ID: id=20, offset=0, size=32 -> ((32-1)<<11)|20 = 63508
        const unsigned xcd = (unsigned)__builtin_amdgcn_s_getreg(63508) & 7u;
        int s = __hip_atomic_fetch_add(&cnt[xcd], 1, __ATOMIC_RELAXED, __HIP_MEMORY_SCOPE_AGENT);
        int slot;
        if (s < 16) {
            slot = (int)xcd * 16 + s;
        } else {
            int o = __hip_atomic_fetch_add(ovf, 1, __ATOMIC_RELAXED, __HIP_MEMORY_SCOPE_AGENT);
            int it = 0;
            for (;;) {                                    // wait all 128 arrived
                int tot = 0;
                for (int i = 0; i < 8; ++i) tot += ld_ag_i32(&cnt[i]);
                if (tot >= 128 || ++it >= NEG_CAP) break;
            }
            int k = o; slot = 0;
            for (int xx = 0; xx < 8; ++xx) {              // o-th unclaimed slot
                int c = ld_ag_i32(&cnt[xx]);
                int cl = c < 16 ? c : 16;
                int fr = 16 - cl;
                if (k < fr) { slot = xx * 16 + cl + k; break; }
                k -= fr;
            }
        }
        const int i = slot & 15;
        sh_g = (slot >> 4) * 2 + (i >> 3);
        sh_m = i & 7;
        st_ag_u32(&table[sh_g * 8 + sh_m], (int)xcd + 1);
    }
    __syncthreads();
    const int g = sh_g, m = sh_m;
    const unsigned nonce = sh_nonce;
    if (tid < NM) {                        // wait own group's 8 entries
        int it = 0;
        while (ld_ag_i32(&table[g * 8 + tid]) == 0 && ++it < NEG_CAP) {}
    }
    __syncthreads();
    if (tid == 0) {
        int v0 = ld_ag_i32(&table[g * 8]);
        int eq = (v0 != 0);
        for (int i = 1; i < 8; ++i) eq &= (ld_ag_i32(&table[g * 8 + i]) == v0);
        sh_fast = eq;
    }
    __syncthreads();
    const int fastg = sh_fast;
    unsigned* flagbase = (unsigned*)(ex + FLAGS_OFF + g * 64);

    // ================= W fragments (wave w owns cols m*64+w*16..+16) ======
    const int wrow = m * 64 + w * 16 + n;
    short8 Whi[18], Wlo[18];
    #pragma unroll
    for (int kt = 0; kt < 18; ++kt) {
        const float* p = (kt < 16) ? (W_hh + wrow * 512 + kt * 32 + quad * 8)
                                   : (W_ih + wrow * 64 + (kt - 16) * 32 + quad * 8);
        #pragma unroll
        for (int jj = 0; jj < 8; ++jj) {
            float f = p[jj];
            unsigned short h = f2bf(f);
            Whi[kt][jj] = (short)h;
            Wlo[kt][jj] = (short)f2bf(f - bf2f(h));
        }
    }
    const float bias_i = b_ih[wrow] + b_hh[wrow];

    // ================= init: zero own chunk (global parity0 + LDS) ========
    {
        const int idx = tid * 16;          // 0..4095 over 4 KB own chunk
        const int pl = idx >> 11, rem = idx & 2047, row = rem >> 7, off = rem & 127;
        unsigned char* gp = ex + g * SLAB + pl * 16384 + row * 1024 + m * 128 + off;
        if (fastg) { *(volatile ull*)gp = 0ull; *(volatile ull*)(gp + 8) = 0ull; }
        else       { st_ag_u64(gp, 0ull);      st_ag_u64(gp + 8, 0ull); }
        *(ull*)(smem + pl * LA_PLANE + row * LA_STRIDE + m * 128 + off)     = 0ull;
        *(ull*)(smem + pl * LA_PLANE + row * LA_STRIDE + m * 128 + off + 8) = 0ull;
    }
    __syncthreads();                       // vmcnt(0): zeros visible (L2/L3)
    if (tid == 0) st_ag_u32(flagbase + m, nonce);

    // ================= recurrence =========================================
    const int xrow = tid >> 4, xi4 = tid & 15;
    for (int t = 0; t < T_STEPS; ++t) {
        // x_t prefetch (independent of flags)
        const float4 xv = *(const float4*)
            (x + ((size_t)(g * 16 + xrow) * T_STEPS + t) * 64 + xi4 * 4);

        // poll 7 partners (flags always L3; skew<=1 by protocol)
        if (tid < 7) {
            const int pm = tid + (tid >= m ? 1 : 0);
            poll_flag(flagbase + pm, nonce + (unsigned)t);
        }
        __syncthreads();                                   // (a)

        // stage 7 partner chunks (28 KB): batched async loads, one wait
        const unsigned char* slab_r = ex + ((t & 1) * NG + g) * SLAB;
        {
            ull v[14]; int la[14];
            #pragma unroll
            for (int r = 0; r < 14; ++r) {
                const int c = r * 256 + tid;              // 0..3583
                const int p = c >> 9, rem = c & 511;
                const int pl = rem >> 8, rem2 = rem & 255;
                const int row = rem2 >> 4, col8 = rem2 & 15;
                const int pm = p + (p >= m ? 1 : 0);
                const unsigned char* gp = slab_r + pl * 16384 + row * 1024 + pm * 128 + col8 * 8;
                la[r] = pl * LA_PLANE + row * LA_STRIDE + pm * 128 + col8 * 8;
                v[r] = fastg ? ld_l2_u64_async(gp) : ld_l3_u64_async(gp);
            }
            wait_vm0();
            #pragma unroll
            for (int r = 0; r < 14; ++r) *(ull*)(smem + la[r]) = v[r];
        }
        // stage x_t (fp32 -> bf16 hi/lo)
        {
            bfx4 hi4, lo4;
            #pragma unroll
            for (int k = 0; k < 4; ++k) {
                float f = (k == 0) ? xv.x : (k == 1) ? xv.y : (k == 2) ? xv.z : xv.w;
                unsigned short h = f2bf(f);
                hi4[k] = h;
                lo4[k] = f2bf(f - bf2f(h));
            }
            *(bfx4*)(smem + LX_OFF + xrow * LX_STRIDE + xi4 * 8) = hi4;
            *(bfx4*)(smem + LX_OFF + LX_PLANE + xrow * LX_STRIDE + xi4 * 8) = lo4;
        }
        __syncthreads();                                   // (b)

        // compute C[16 x 16] over K=576, bf16x3
        floatx4 c0 = {0.f,0.f,0.f,0.f}, c1 = {0.f,0.f,0.f,0.f}, c2 = {0.f,0.f,0.f,0.f};
        #pragma unroll
        for (int kt = 0; kt < 16; ++kt) {
            const unsigned char* ba = smem + n * LA_STRIDE + kt * 64 + quad * 16;
            short8 ah = *(const short8*)(ba);
            short8 al = *(const short8*)(ba + LA_PLANE);
            c0 = __builtin_amdgcn_mfma_f32_16x16x32_bf16(ah, Whi[kt], c0, 0, 0, 0);
            c1 = __builtin_amdgcn_mfma_f32_16x16x32_bf16(al, Whi[kt], c1, 0, 0, 0);
            c2 = __builtin_amdgcn_mfma_f32_16x16x32_bf16(ah, Wlo[kt], c2, 0, 0, 0);
        }
        #pragma unroll
        for (int kt = 16; kt < 18; ++kt) {
            const unsigned char* ba = smem + LX_OFF + n * LX_STRIDE + (kt - 16) * 64 + quad * 16;
            short8 ah = *(const short8*)(ba);
            short8 al = *(const short8*)(ba + LX_PLANE);
            c0 = __builtin_amdgcn_mfma_f32_16x16x32_bf16(ah, Whi[kt], c0, 0, 0, 0);
            c1 = __builtin_amdgcn_mfma_f32_16x16x32_bf16(al, Whi[kt], c1, 0, 0, 0);
            c2 = __builtin_amdgcn_mfma_f32_16x16x32_bf16(ah, Wlo[kt], c2, 0, 0, 0);
        }

        // epilogue: h_{t+1} -> global (partners); no LDS writes yet
        unsigned char* slab_w = ex + (((t + 1) & 1) * NG + g) * SLAB;
        const floatx4 cs = c0 + c1 + c2;
        float vv[4]; unsigned short hh[4], ll[4];
        #pragma unroll
        for (int r = 0; r < 4; ++r) {
            float v = cs[r] + bias_i;
            v = v > 0.f ? v : 0.f;
            vv[r] = v;
            hh[r] = f2bf(v);
            ll[r] = f2bf(v - bf2f(hh[r]));
            const int row = quad * 4 + r;
            if (fastg) {
                *(volatile unsigned short*)(slab_w + row * 1024 + wrow * 2) = hh[r];
                *(volatile unsigned short*)(slab_w + 16384 + row * 1024 + wrow * 2) = ll[r];
            } else {
                st_ag_u16(slab_w + row * 1024 + wrow * 2, hh[r]);
                st_ag_u16(slab_w + 16384 + row * 1024 + wrow * 2, ll[r]);
            }
        }
        __syncthreads();   // (c): MFMA reads done + all global stores drained

        // flag out early; own-chunk LDS writes ordered by next (a)/(b)
        if (tid == 0) st_ag_u32(flagbase + m, nonce + (unsigned)t + 1u);
        #pragma unroll
        for (int r = 0; r < 4; ++r) {
            const int row = quad * 4 + r;
            *(unsigned short*)(smem + 0 * LA_PLANE + row * LA_STRIDE + wrow * 2) = hh[r];
            *(unsigned short*)(smem + 1 * LA_PLANE + row * LA_STRIDE + wrow * 2) = ll[r];
        }
        (void)vv;
    }

    // ================= fc on h_T (member 0 only) ==========================
    if (m != 0) return;
    if (tid < 7) poll_flag(flagbase + (tid + 1), nonce + (unsigned)T_STEPS);
    __syncthreads();
    {   // stage parity-0 partner chunks (own chunk already in LDS)
        const unsigned char* slab_r = ex + (0 * NG + g) * SLAB;
        ull v[14]; int la[14];
        #pragma unroll
        for (int r = 0; r < 14; ++r) {
            const int c = r * 256 + tid;
            const int p = c >> 9, rem = c & 511;
            const int pl = rem >> 8, rem2 = rem & 255;
            const int row = rem2 >> 4, col8 = rem2 & 15;
            const int pm = p + 1;                          // m == 0
            const unsigned char* gp = slab_r + pl * 16384 + row * 1024 + pm * 128 + col8 * 8;
            la[r] = pl * LA_PLANE + row * LA_STRIDE + pm * 128 + col8 * 8;
            v[r] = fastg ? ld_l2_u64_async(gp) : ld_l3_u64_async(gp);
        }
        wait_vm0();
        #pragma unroll
        for (int r = 0; r < 14; ++r) *(ull*)(smem + la[r]) = v[r];
    }
    __syncthreads();
    for (int idx = tid; idx < 384; idx += 256) {
        const int row = idx / 24, o = idx % 24;
        const float* wp = fc_w + o * 512;
        float s = 0.f;
        for (int k = 0; k < 512; k += 4) {
            bfx4 hv = *(const bfx4*)(smem + row * LA_STRIDE + k * 2);
            bfx4 lv = *(const bfx4*)(smem + LA_PLANE + row * LA_STRIDE + k * 2);
            const float4 wv = *(const float4*)(wp + k);
            s += (bf2f(hv[0]) + bf2f(lv[0])) * wv.x;
            s += (bf2f(hv[1]) + bf2f(lv[1])) * wv.y;
            s += (bf2f(hv[2]) + bf2f(lv[2])) * wv.z;
            s += (bf2f(hv[3]) + bf2f(lv[3])) * wv.w;
        }
        out[(g * 16 + row) * 24 + o] = s + fc_b[o];
    }
}

extern "C" void kernel_launch(void* const* d_in, const int* in_sizes, int n_in,
                              void* d_out, int out_size, void* d_ws, size_t ws_size,
                              hipStream_t stream) {
    (void)in_sizes; (void)n_in; (void)out_size; (void)ws_size;
    const float* x    = (const float*)d_in[0];
    const float* W_ih = (const float*)d_in[1];
    const float* W_hh = (const float*)d_in[2];
    const float* b_ih = (const float*)d_in[3];
    const float* b_hh = (const float*)d_in[4];
    const float* fc_w = (const float*)d_in[5];
    const float* fc_b = (const float*)d_in[6];
    rnn_persistent<<<128, 256, 0, stream>>>(x, W_ih, W_hh, b_ih, b_hh,
                                            fc_w, fc_b, (float*)d_out,
                                            (unsigned char*)d_ws);
}